// Round 2
// baseline (1073.598 us; speedup 1.0000x reference)
//
#include <hip/hip_runtime.h>

// Problem constants: B=64, T=256, V=4096, H=512
// Inputs: x[B*T] i32, Wxh[V,H] f32, Whh[H,H] f32, bh[H] f32, Wo[H,V] f32, Bo[V] f32
// Output: out[B,T,V] f32 = (scan hs) @ Wo + Bo

typedef __fp16 half2_t __attribute__((ext_vector_type(2)));  // clang builtin half type
typedef __attribute__((ext_vector_type(8))) short short8;   // 8 bf16 = 4 VGPRs (MFMA A/B frag)
typedef __attribute__((ext_vector_type(4))) float f32x4;    // MFMA C/D frag

__device__ __forceinline__ unsigned short f32_to_bf16(float f) {
  unsigned int u = __builtin_bit_cast(unsigned int, f);
  u = (u + 0x7FFFu + ((u >> 16) & 1u)) >> 16;  // RNE
  return (unsigned short)u;
}

__device__ __forceinline__ unsigned int pack_f16x2(float a, float b) {
  half2_t h = __builtin_amdgcn_cvt_pkrtz(a, b);  // v_cvt_pkrtz_f16_f32
  return __builtin_bit_cast(unsigned int, h);
}

__device__ __forceinline__ float fdot2_(unsigned int w, unsigned int h, float acc) {
  return __builtin_amdgcn_fdot2(__builtin_bit_cast(half2_t, w),
                                __builtin_bit_cast(half2_t, h), acc, false);
}

__device__ __forceinline__ void glds16(const void* g, void* lds) {
  // async global->LDS, 16B per lane; lds must be wave-uniform base (dest = base + lane*16)
  __builtin_amdgcn_global_load_lds(
      (const __attribute__((address_space(1))) unsigned int*)g,
      (__attribute__((address_space(3))) unsigned int*)lds, 16, 0, 0);
}

// ---------------------------------------------------------------------------
// Prep 1: Whh [i][j] f32 -> WhhP[k][j] u32 = pack_f16(Whh[2k][j], Whh[2k+1][j])
// ---------------------------------------------------------------------------
__global__ __launch_bounds__(256) void pack_whh(const float* __restrict__ Whh,
                                                unsigned int* __restrict__ WhhP) {
  int idx = blockIdx.x * 256 + threadIdx.x;  // 131072 total
  int k = idx >> 9, j = idx & 511;
  float f0 = Whh[(2 * k) * 512 + j];
  float f1 = Whh[(2 * k + 1) * 512 + j];
  WhhP[idx] = pack_f16x2(f0, f1);
}

// ---------------------------------------------------------------------------
// Prep 2: Wo [h][v] f32 -> WoT [v][h] bf16 (transposed for MFMA B-frag reads)
// ---------------------------------------------------------------------------
__global__ __launch_bounds__(256) void transpose_wo(const float* __restrict__ Wo,
                                                    unsigned short* __restrict__ WoT) {
  __shared__ float tile[64][65];
  const int tv = blockIdx.x;   // 0..63  (V/64)
  const int th = blockIdx.y;   // 0..7   (H/64)
  const int tid = threadIdx.x;
  const int c = tid & 63, r4 = tid >> 6;
#pragma unroll
  for (int p = 0; p < 16; ++p) {
    int hl = p * 4 + r4;
    tile[hl][c] = Wo[(size_t)(th * 64 + hl) * 4096 + tv * 64 + c];  // coalesced read
  }
  __syncthreads();
#pragma unroll
  for (int p = 0; p < 16; ++p) {
    int vl = p * 4 + r4;
    WoT[(size_t)(tv * 64 + vl) * 512 + th * 64 + c] = f32_to_bf16(tile[c][vl]);  // coalesced write
  }
}

// ---------------------------------------------------------------------------
// Recurrence: one block per batch element. Whh column j in VGPRs (f16 pairs),
// h state broadcast from LDS, v_dot2_f32_f16 inner product, f32 accumulate.
// Writes hs[b*T+t][j] as bf16 (GEMM A matrix).
// ---------------------------------------------------------------------------
__global__ __launch_bounds__(512, 1) void rnn_scan(const int* __restrict__ x,
                                                   const float* __restrict__ Wxh,
                                                   const unsigned int* __restrict__ WhhP,
                                                   const float* __restrict__ bh,
                                                   unsigned short* __restrict__ hs) {
  __shared__ uint4 hbuf4[64];   // 512 h values as 256 packed f16 pairs
  __shared__ int toks[256];
  const int b = blockIdx.x;
  const int j = threadIdx.x;

  // Register-resident column j of Whh: w[k] = (Whh[2k][j], Whh[2k+1][j]) f16x2
  unsigned int w[256];
#pragma unroll
  for (int k = 0; k < 256; ++k) w[k] = WhhP[k * 512 + j];  // coalesced

  if (j < 64) hbuf4[j] = make_uint4(0u, 0u, 0u, 0u);       // h0 = 0
  if (j < 256) toks[j] = x[b * 256 + j];
  const float bhj = bh[j];
  __syncthreads();

  const uint4* hb4 = (const uint4*)hbuf4;
  unsigned short* hb16 = (unsigned short*)hbuf4;

  for (int t = 0; t < 256; ++t) {
    const int tok = toks[t];
    const float xv = Wxh[(size_t)tok * 512 + j];  // L2-hot gather row, coalesced
    float a0 = 0.f, a1 = 0.f, a2 = 0.f, a3 = 0.f;
#pragma unroll
    for (int k4 = 0; k4 < 64; ++k4) {
      const uint4 hp = hb4[k4];  // ds_read_b128, all lanes same addr -> broadcast
      a0 = fdot2_(w[4 * k4 + 0], hp.x, a0);
      a1 = fdot2_(w[4 * k4 + 1], hp.y, a1);
      a2 = fdot2_(w[4 * k4 + 2], hp.z, a2);
      a3 = fdot2_(w[4 * k4 + 3], hp.w, a3);
    }
    const float u = xv + ((a0 + a1) + (a2 + a3)) + bhj;
    const float h = tanhf(u);
    hs[(size_t)(b * 256 + t) * 512 + j] = f32_to_bf16(h);  // coalesced u16 store
    __syncthreads();  // all lanes done reading h_t
    unsigned short hbits;
    {
      half2_t hp2 = __builtin_amdgcn_cvt_pkrtz(h, h);
      unsigned int hu = __builtin_bit_cast(unsigned int, hp2);
      hbits = (unsigned short)(hu & 0xFFFFu);
    }
    hb16[j] = hbits;
    __syncthreads();  // h_{t+1} visible
  }
}

// ---------------------------------------------------------------------------
// Output GEMM: C[16384,4096] = A[16384,512](bf16) @ WoT^T + Bo.
// m97 structure: 128x128 tile, BK=32, 256 thr (2x2 waves, 64x64 each),
// global_load_lds w16 staging, mfma_f32_16x16x32_bf16.
// ---------------------------------------------------------------------------
__global__ __launch_bounds__(256) void gemm_out(const unsigned short* __restrict__ A,
                                                const unsigned short* __restrict__ Bt,
                                                const float* __restrict__ Bo,
                                                float* __restrict__ C) {
  __shared__ alignas(16) unsigned short As[128 * 32];
  __shared__ alignas(16) unsigned short Bs[128 * 32];
  const int tid = threadIdx.x;
  const int lane = tid & 63, wid = tid >> 6;
  const int bn = blockIdx.x & 31, bm = blockIdx.x >> 5;
  const int wr = wid >> 1, wc = wid & 1;

  f32x4 acc[4][4] = {};

  // staging: thread covers row (tid>>2) of a 64-row pass, k-chunk (tid&3)*8
  const unsigned short* Ag = A + (size_t)(bm * 128 + (tid >> 2)) * 512 + (tid & 3) * 8;
  const unsigned short* Bg = Bt + (size_t)(bn * 128 + (tid >> 2)) * 512 + (tid & 3) * 8;
  char* AsW = (char*)As + wid * 1024;  // wave-uniform LDS dest
  char* BsW = (char*)Bs + wid * 1024;

  const int laneRow = lane & 15;
  const int k0 = (lane >> 4) * 8;

  for (int kt = 0; kt < 16; ++kt) {
    __syncthreads();  // previous compute done before overwrite
    const unsigned short* a0 = Ag + kt * 32;
    const unsigned short* b0 = Bg + kt * 32;
    glds16(a0,            AsW);
    glds16(a0 + 64 * 512, AsW + 4096);
    glds16(b0,            BsW);
    glds16(b0 + 64 * 512, BsW + 4096);
    __syncthreads();  // compiler drains vmcnt before barrier

    short8 af[4], bf[4];
#pragma unroll
    for (int f = 0; f < 4; ++f)
      af[f] = *(const short8*)&As[(wr * 64 + f * 16 + laneRow) * 32 + k0];
#pragma unroll
    for (int f = 0; f < 4; ++f)
      bf[f] = *(const short8*)&Bs[(wc * 64 + f * 16 + laneRow) * 32 + k0];
#pragma unroll
    for (int fm = 0; fm < 4; ++fm)
#pragma unroll
      for (int fn = 0; fn < 4; ++fn)
        acc[fm][fn] = __builtin_amdgcn_mfma_f32_16x16x32_bf16(af[fm], bf[fn], acc[fm][fn], 0, 0, 0);
  }

  // epilogue: C/D layout col=lane&15, row=(lane>>4)*4+reg  [m89-verified]
  const int mg0 = bm * 128 + wr * 64, ng0 = bn * 128 + wc * 64;
#pragma unroll
  for (int fn = 0; fn < 4; ++fn) {
    const int col = ng0 + fn * 16 + laneRow;
    const float bo = Bo[col];
#pragma unroll
    for (int fm = 0; fm < 4; ++fm) {
      const int row0 = mg0 + fm * 16 + (lane >> 4) * 4;
#pragma unroll
      for (int r = 0; r < 4; ++r)
        C[(size_t)(row0 + r) * 4096 + col] = acc[fm][fn][r] + bo;
    }
  }
}

// ---------------------------------------------------------------------------
extern "C" void kernel_launch(void* const* d_in, const int* in_sizes, int n_in,
                              void* d_out, int out_size, void* d_ws, size_t ws_size,
                              hipStream_t stream) {
  (void)in_sizes; (void)n_in; (void)out_size; (void)ws_size;
  const int* x = (const int*)d_in[0];
  const float* Wxh = (const float*)d_in[1];
  const float* Whh = (const float*)d_in[2];
  const float* bh = (const float*)d_in[3];
  const float* Wo = (const float*)d_in[4];
  const float* Bo = (const float*)d_in[5];
  float* out = (float*)d_out;

  // workspace: WhhP 512KB | WoT 4MB | hs 16MB  (total 20.5 MB)
  unsigned int* WhhP = (unsigned int*)d_ws;
  unsigned short* WoT = (unsigned short*)((char*)d_ws + (512u << 10));
  unsigned short* hs = (unsigned short*)((char*)d_ws + (512u << 10) + (4u << 20));

  hipLaunchKernelGGL(pack_whh, dim3(512), dim3(256), 0, stream, Whh, WhhP);
  hipLaunchKernelGGL(transpose_wo, dim3(64, 8), dim3(256), 0, stream, Wo, WoT);
  hipLaunchKernelGGL(rnn_scan, dim3(64), dim3(512), 0, stream, x, Wxh, WhhP, bh, hs);
  hipLaunchKernelGGL(gemm_out, dim3(4096), dim3(256), 0, stream, hs, WoT, Bo, out);
}

// Round 3
// 1054.896 us; speedup vs baseline: 1.0177x; 1.0177x over previous
//
#include <hip/hip_runtime.h>

// Problem constants: B=64, T=256, V=4096, H=512
// Inputs: x[B*T] i32, Wxh[V,H] f32, Whh[H,H] f32, bh[H] f32, Wo[H,V] f32, Bo[V] f32
// Output: out[B,T,V] f32 = (scan hs) @ Wo + Bo

typedef __fp16 half2_t __attribute__((ext_vector_type(2)));  // clang builtin half type
typedef __attribute__((ext_vector_type(8))) short short8;   // 8 bf16 = 4 VGPRs (MFMA A/B frag)
typedef __attribute__((ext_vector_type(4))) float f32x4;    // MFMA C/D frag

__device__ __forceinline__ unsigned short f32_to_bf16(float f) {
  unsigned int u = __builtin_bit_cast(unsigned int, f);
  u = (u + 0x7FFFu + ((u >> 16) & 1u)) >> 16;  // RNE
  return (unsigned short)u;
}

__device__ __forceinline__ unsigned int pack_f16x2(float a, float b) {
  half2_t h = __builtin_amdgcn_cvt_pkrtz(a, b);  // v_cvt_pkrtz_f16_f32
  return __builtin_bit_cast(unsigned int, h);
}

__device__ __forceinline__ float fdot2_(unsigned int w, unsigned int h, float acc) {
  return __builtin_amdgcn_fdot2(__builtin_bit_cast(half2_t, w),
                                __builtin_bit_cast(half2_t, h), acc, false);
}

__device__ __forceinline__ void glds16(const void* g, void* lds) {
  // async global->LDS, 16B per lane; lds must be wave-uniform base (dest = base + lane*16)
  __builtin_amdgcn_global_load_lds(
      (const __attribute__((address_space(1))) unsigned int*)g,
      (__attribute__((address_space(3))) unsigned int*)lds, 16, 0, 0);
}

// ---------------------------------------------------------------------------
// Prep 1: Whh [i][j] f32 -> WhhP2: uint4-friendly layout.
// u32 element at flat idx = k4*2048 + j*4 + c  packs (Whh[2k][j], Whh[2k+1][j])
// where pair index k = 4*k4 + c.  So WhhP2_4[k4*512 + j] is a uint4 holding
// pairs 4k4..4k4+3 (h-elements 8k4..8k4+7) of column j.
// ---------------------------------------------------------------------------
__global__ __launch_bounds__(256) void pack_whh(const float* __restrict__ Whh,
                                                unsigned int* __restrict__ WhhP2) {
  int idx = blockIdx.x * 256 + threadIdx.x;  // 131072 total u32
  int c = idx & 3;
  int j = (idx >> 2) & 511;
  int k4 = idx >> 11;
  int k = k4 * 4 + c;  // pair index 0..255
  float f0 = Whh[(2 * k) * 512 + j];
  float f1 = Whh[(2 * k + 1) * 512 + j];
  WhhP2[idx] = pack_f16x2(f0, f1);
}

// ---------------------------------------------------------------------------
// Prep 2: Wo [h][v] f32 -> WoT [v][h] bf16 (transposed for MFMA B-frag reads)
// ---------------------------------------------------------------------------
__global__ __launch_bounds__(256) void transpose_wo(const float* __restrict__ Wo,
                                                    unsigned short* __restrict__ WoT) {
  __shared__ float tile[64][65];
  const int tv = blockIdx.x;   // 0..63  (V/64)
  const int th = blockIdx.y;   // 0..7   (H/64)
  const int tid = threadIdx.x;
  const int c = tid & 63, r4 = tid >> 6;
#pragma unroll
  for (int p = 0; p < 16; ++p) {
    int hl = p * 4 + r4;
    tile[hl][c] = Wo[(size_t)(th * 64 + hl) * 4096 + tv * 64 + c];  // coalesced read
  }
  __syncthreads();
#pragma unroll
  for (int p = 0; p < 16; ++p) {
    int vl = p * 4 + r4;
    WoT[(size_t)(tv * 64 + vl) * 512 + th * 64 + c] = f32_to_bf16(tile[c][vl]);  // coalesced write
  }
}

// ---------------------------------------------------------------------------
// Recurrence: one block per batch element, 1024 threads (16 waves).
// Thread (j = tid&511, half = tid>>9) holds HALF of Whh column j as 32 uint4
// (128 VGPRs of f16 pairs) -- small enough that the 32-trip init loop fully
// unrolls and the array provably stays in registers (R2 post-mortem: the
// 256-trip version didn't unroll -> scratch -> 982us at VALUBusy 6%).
// h state broadcast from LDS; halves combine partial dots via LDS.
// ---------------------------------------------------------------------------
__global__ __launch_bounds__(1024, 4) void rnn_scan(const int* __restrict__ x,
                                                    const float* __restrict__ Wxh,
                                                    const unsigned int* __restrict__ WhhP2,
                                                    const float* __restrict__ bh,
                                                    unsigned short* __restrict__ hs) {
  __shared__ uint4 hbuf4[64];   // 512 h values as 256 packed f16 pairs
  __shared__ float pbuf[512];   // half=1 partial sums
  __shared__ int toks[256];
  const int b = blockIdx.x;
  const int tid = threadIdx.x;
  const int j = tid & 511;
  const int half = tid >> 9;

  // 32 coalesced dwordx4 loads: pairs [128*half, 128*half+128) of column j
  const uint4* W4 = (const uint4*)WhhP2;
  uint4 w4[32];
#pragma unroll
  for (int i = 0; i < 32; ++i) w4[i] = W4[(size_t)(32 * half + i) * 512 + j];

  if (tid < 64) hbuf4[tid] = make_uint4(0u, 0u, 0u, 0u);  // h0 = 0
  if (tid < 256) toks[tid] = x[b * 256 + tid];
  const float bhj = bh[j];
  __syncthreads();

  unsigned short* hb16 = (unsigned short*)hbuf4;
  const uint4* hb = hbuf4 + 32 * half;  // wave-uniform half (waves 0-7: half 0)

  for (int t = 0; t < 256; ++t) {
    const int tok = toks[t];
    const float xv = Wxh[(size_t)tok * 512 + j];  // L2/L3-hot row, coalesced
    float a0 = 0.f, a1 = 0.f, a2 = 0.f, a3 = 0.f;
#pragma unroll
    for (int i = 0; i < 32; ++i) {
      const uint4 hp = hb[i];  // ds_read_b128, all lanes same addr -> broadcast
      a0 = fdot2_(w4[i].x, hp.x, a0);
      a1 = fdot2_(w4[i].y, hp.y, a1);
      a2 = fdot2_(w4[i].z, hp.z, a2);
      a3 = fdot2_(w4[i].w, hp.w, a3);
    }
    const float part = (a0 + a1) + (a2 + a3);
    if (half) pbuf[j] = part;
    __syncthreads();  // partials visible; all hbuf reads of step t complete
    if (!half) {
      const float u = xv + part + pbuf[j] + bhj;
      const float h = tanhf(u);
      hs[(size_t)(b * 256 + t) * 512 + j] = f32_to_bf16(h);  // coalesced u16 store
      half2_t hp2 = __builtin_amdgcn_cvt_pkrtz(h, h);
      unsigned int hu = __builtin_bit_cast(unsigned int, hp2);
      hb16[j] = (unsigned short)(hu & 0xFFFFu);
    }
    __syncthreads();  // h_{t+1} visible to all
  }
}

// ---------------------------------------------------------------------------
// Output GEMM: C[16384,4096] = A[16384,512](bf16) @ WoT^T + Bo.
// m97 structure: 128x128 tile, BK=32, 256 thr (2x2 waves, 64x64 each),
// global_load_lds w16 staging, mfma_f32_16x16x32_bf16.
// ---------------------------------------------------------------------------
__global__ __launch_bounds__(256) void gemm_out(const unsigned short* __restrict__ A,
                                                const unsigned short* __restrict__ Bt,
                                                const float* __restrict__ Bo,
                                                float* __restrict__ C) {
  __shared__ alignas(16) unsigned short As[128 * 32];
  __shared__ alignas(16) unsigned short Bs[128 * 32];
  const int tid = threadIdx.x;
  const int lane = tid & 63, wid = tid >> 6;
  const int bn = blockIdx.x & 31, bm = blockIdx.x >> 5;
  const int wr = wid >> 1, wc = wid & 1;

  f32x4 acc[4][4] = {};

  // staging: thread covers row (tid>>2) of a 64-row pass, k-chunk (tid&3)*8
  const unsigned short* Ag = A + (size_t)(bm * 128 + (tid >> 2)) * 512 + (tid & 3) * 8;
  const unsigned short* Bg = Bt + (size_t)(bn * 128 + (tid >> 2)) * 512 + (tid & 3) * 8;
  char* AsW = (char*)As + wid * 1024;  // wave-uniform LDS dest
  char* BsW = (char*)Bs + wid * 1024;

  const int laneRow = lane & 15;
  const int k0 = (lane >> 4) * 8;

  for (int kt = 0; kt < 16; ++kt) {
    __syncthreads();  // previous compute done before overwrite
    const unsigned short* a0 = Ag + kt * 32;
    const unsigned short* b0 = Bg + kt * 32;
    glds16(a0,            AsW);
    glds16(a0 + 64 * 512, AsW + 4096);
    glds16(b0,            BsW);
    glds16(b0 + 64 * 512, BsW + 4096);
    __syncthreads();  // compiler drains vmcnt before barrier

    short8 af[4], bf[4];
#pragma unroll
    for (int f = 0; f < 4; ++f)
      af[f] = *(const short8*)&As[(wr * 64 + f * 16 + laneRow) * 32 + k0];
#pragma unroll
    for (int f = 0; f < 4; ++f)
      bf[f] = *(const short8*)&Bs[(wc * 64 + f * 16 + laneRow) * 32 + k0];
#pragma unroll
    for (int fm = 0; fm < 4; ++fm)
#pragma unroll
      for (int fn = 0; fn < 4; ++fn)
        acc[fm][fn] = __builtin_amdgcn_mfma_f32_16x16x32_bf16(af[fm], bf[fn], acc[fm][fn], 0, 0, 0);
  }

  // epilogue: C/D layout col=lane&15, row=(lane>>4)*4+reg  [m89-verified]
  const int mg0 = bm * 128 + wr * 64, ng0 = bn * 128 + wc * 64;
#pragma unroll
  for (int fn = 0; fn < 4; ++fn) {
    const int col = ng0 + fn * 16 + laneRow;
    const float bo = Bo[col];
#pragma unroll
    for (int fm = 0; fm < 4; ++fm) {
      const int row0 = mg0 + fm * 16 + (lane >> 4) * 4;
#pragma unroll
      for (int r = 0; r < 4; ++r)
        C[(size_t)(row0 + r) * 4096 + col] = acc[fm][fn][r] + bo;
    }
  }
}

// ---------------------------------------------------------------------------
extern "C" void kernel_launch(void* const* d_in, const int* in_sizes, int n_in,
                              void* d_out, int out_size, void* d_ws, size_t ws_size,
                              hipStream_t stream) {
  (void)in_sizes; (void)n_in; (void)out_size; (void)ws_size;
  const int* x = (const int*)d_in[0];
  const float* Wxh = (const float*)d_in[1];
  const float* Whh = (const float*)d_in[2];
  const float* bh = (const float*)d_in[3];
  const float* Wo = (const float*)d_in[4];
  const float* Bo = (const float*)d_in[5];
  float* out = (float*)d_out;

  // workspace: WhhP2 512KB | WoT 4MB | hs 16MB  (total 20.5 MB)
  unsigned int* WhhP2 = (unsigned int*)d_ws;
  unsigned short* WoT = (unsigned short*)((char*)d_ws + (512u << 10));
  unsigned short* hs = (unsigned short*)((char*)d_ws + (512u << 10) + (4u << 20));

  hipLaunchKernelGGL(pack_whh, dim3(512), dim3(256), 0, stream, Whh, WhhP2);
  hipLaunchKernelGGL(transpose_wo, dim3(64, 8), dim3(256), 0, stream, Wo, WoT);
  hipLaunchKernelGGL(rnn_scan, dim3(64), dim3(1024), 0, stream, x, Wxh, WhhP2, bh, hs);
  hipLaunchKernelGGL(gemm_out, dim3(4096), dim3(256), 0, stream, hs, WoT, Bo, out);
}

// Round 4
// 726.215 us; speedup vs baseline: 1.4783x; 1.4526x over previous
//
#include <hip/hip_runtime.h>

// Problem constants: B=64, T=256, V=4096, H=512
// Inputs: x[B*T] i32, Wxh[V,H] f32, Whh[H,H] f32, bh[H] f32, Wo[H,V] f32, Bo[V] f32
// Output: out[B,T,V] f32 = (scan hs) @ Wo + Bo

typedef __fp16 half2_t __attribute__((ext_vector_type(2)));  // clang builtin half type
typedef __attribute__((ext_vector_type(8))) short short8;   // 8 bf16 = 4 VGPRs (MFMA A/B frag)
typedef __attribute__((ext_vector_type(4))) float f32x4;    // MFMA C/D frag

__device__ __forceinline__ unsigned short f32_to_bf16(float f) {
  unsigned int u = __builtin_bit_cast(unsigned int, f);
  u = (u + 0x7FFFu + ((u >> 16) & 1u)) >> 16;  // RNE
  return (unsigned short)u;
}

__device__ __forceinline__ unsigned int pack_f16x2(float a, float b) {
  half2_t h = __builtin_amdgcn_cvt_pkrtz(a, b);  // v_cvt_pkrtz_f16_f32
  return __builtin_bit_cast(unsigned int, h);
}

__device__ __forceinline__ float fdot2_(unsigned int w, unsigned int h, float acc) {
  return __builtin_amdgcn_fdot2(__builtin_bit_cast(half2_t, w),
                                __builtin_bit_cast(half2_t, h), acc, false);
}

__device__ __forceinline__ void glds16(const void* g, void* lds) {
  // async global->LDS, 16B per lane; lds must be wave-uniform base (dest = base + lane*16)
  __builtin_amdgcn_global_load_lds(
      (const __attribute__((address_space(1))) unsigned int*)g,
      (__attribute__((address_space(3))) unsigned int*)lds, 16, 0, 0);
}

// ---------------------------------------------------------------------------
// Prep 1: Whh [i][j] f32 -> WhhP2 u32 layout: flat idx = k4*2048 + j*4 + c
// packs pair k = 4*k4+c of column j, i.e. ((uint4*)WhhP2)[k4*512+j] holds
// h-pairs 4k4..4k4+3 (h elements 8k4..8k4+7) of column j.
// ---------------------------------------------------------------------------
__global__ __launch_bounds__(256) void pack_whh(const float* __restrict__ Whh,
                                                unsigned int* __restrict__ WhhP2) {
  int idx = blockIdx.x * 256 + threadIdx.x;  // 131072 total u32
  int c = idx & 3;
  int j = (idx >> 2) & 511;
  int k4 = idx >> 11;
  int k = k4 * 4 + c;  // pair index 0..255
  float f0 = Whh[(2 * k) * 512 + j];
  float f1 = Whh[(2 * k + 1) * 512 + j];
  WhhP2[idx] = pack_f16x2(f0, f1);
}

// ---------------------------------------------------------------------------
// Prep 2: Wo [h][v] f32 -> WoT [v][h] bf16 (transposed for MFMA B-frag reads)
// ---------------------------------------------------------------------------
__global__ __launch_bounds__(256) void transpose_wo(const float* __restrict__ Wo,
                                                    unsigned short* __restrict__ WoT) {
  __shared__ float tile[64][65];
  const int tv = blockIdx.x;   // 0..63  (V/64)
  const int th = blockIdx.y;   // 0..7   (H/64)
  const int tid = threadIdx.x;
  const int c = tid & 63, r4 = tid >> 6;
#pragma unroll
  for (int p = 0; p < 16; ++p) {
    int hl = p * 4 + r4;
    tile[hl][c] = Wo[(size_t)(th * 64 + hl) * 4096 + tv * 64 + c];  // coalesced read
  }
  __syncthreads();
#pragma unroll
  for (int p = 0; p < 16; ++p) {
    int vl = p * 4 + r4;
    WoT[(size_t)(tv * 64 + vl) * 512 + th * 64 + c] = f32_to_bf16(tile[c][vl]);  // coalesced write
  }
}

// ---------------------------------------------------------------------------
// Recurrence: one block per batch element, 512 threads (8 waves = 2/SIMD,
// HARD VGPR cap 256/wave -- R2/R3 spilled because their budgets exceeded the
// cap). Thread j owns output j. Whh column j: 128 pairs register-resident
// (w4[32] uint4 = 128 VGPR), 128 pairs STREAMED from L2 each step through a
// 12-uint4 rotating pipeline (48 VGPR in flight, all-static indices).
// h state: double-buffered LDS f16 pairs, broadcast ds_read_b128, 1 barrier
// per step. asm memory clobber per step blocks TBAA-hoisting of the
// loop-invariant stream loads (the R2/R3 scratch trigger).
// ---------------------------------------------------------------------------
__global__ __launch_bounds__(512, 2) void rnn_scan(const int* __restrict__ x,
                                                   const float* Wxh,
                                                   const unsigned int* WhhP2,
                                                   const float* __restrict__ bh,
                                                   unsigned short* hs) {
  __shared__ uint4 hbuf4[2][64];  // 2 x 512 h values as f16 pairs
  __shared__ int toks[256];
  const int b = blockIdx.x;
  const int j = threadIdx.x;  // 0..511
  const uint4* W4 = (const uint4*)WhhP2;

  // Register-resident pairs 0..127 (k4 = 0..31) of column j: 32 coalesced x4 loads
  uint4 w4[32];
#pragma unroll
  for (int i = 0; i < 32; ++i) w4[i] = W4[(size_t)i * 512 + j];

  if (j < 64) hbuf4[0][j] = make_uint4(0u, 0u, 0u, 0u);  // h0 = 0
  if (j < 256) toks[j] = x[b * 256 + j];
  const float bhj = bh[j];
  __syncthreads();

  unsigned short* hb16all = (unsigned short*)hbuf4;  // [2][512] u16 view

  for (int t = 0; t < 256; ++t) {
    asm volatile("" ::: "memory");  // block cross-iteration hoist of stream loads
    const int cur = t & 1;
    const uint4* hb = hbuf4[cur];
    const int tok = toks[t];

    // stream pipeline prologue: 12 uint4 in flight (pairs 128..175)
    uint4 s[12];
#pragma unroll
    for (int u = 0; u < 12; ++u) s[u] = W4[(size_t)(32 + u) * 512 + j];

    const float xv = Wxh[(size_t)tok * 512 + j];  // L2-hot row, coalesced

    float a0 = 0.f, a1 = 0.f, a2 = 0.f, a3 = 0.f;
    // register-resident half (stream latency hides under this)
#pragma unroll
    for (int i = 0; i < 32; ++i) {
      const uint4 hp = hb[i];  // ds_read_b128, all lanes same addr -> broadcast
      a0 = fdot2_(w4[i].x, hp.x, a0);
      a1 = fdot2_(w4[i].y, hp.y, a1);
      a2 = fdot2_(w4[i].z, hp.z, a2);
      a3 = fdot2_(w4[i].w, hp.w, a3);
    }
    // streamed half: consume s[i%12], refill 12 ahead (all indices static)
#pragma unroll
    for (int i = 0; i < 32; ++i) {
      const uint4 sp = s[i % 12];
      const uint4 hp = hb[32 + i];
      a0 = fdot2_(sp.x, hp.x, a0);
      a1 = fdot2_(sp.y, hp.y, a1);
      a2 = fdot2_(sp.z, hp.z, a2);
      a3 = fdot2_(sp.w, hp.w, a3);
      if (i + 12 < 32) s[i % 12] = W4[(size_t)(32 + i + 12) * 512 + j];
    }

    const float u_ = xv + ((a0 + a1) + (a2 + a3)) + bhj;
    const float h = tanhf(u_);
    hs[(size_t)(b * 256 + t) * 512 + j] = f32_to_bf16(h);  // coalesced u16 store
    half2_t hp2 = __builtin_amdgcn_cvt_pkrtz(h, h);
    unsigned int hu = __builtin_bit_cast(unsigned int, hp2);
    hb16all[(cur ^ 1) * 512 + j] = (unsigned short)(hu & 0xFFFFu);  // write next buf
    __syncthreads();  // next buf visible; cur-buf reads all done -> safe to reuse
  }
}

// ---------------------------------------------------------------------------
// Output GEMM: C[16384,4096] = A[16384,512](bf16) @ WoT^T + Bo.
// m97 structure: 128x128 tile, BK=32, 256 thr (2x2 waves, 64x64 each),
// global_load_lds w16 staging, mfma_f32_16x16x32_bf16.
// ---------------------------------------------------------------------------
__global__ __launch_bounds__(256) void gemm_out(const unsigned short* __restrict__ A,
                                                const unsigned short* __restrict__ Bt,
                                                const float* __restrict__ Bo,
                                                float* __restrict__ C) {
  __shared__ alignas(16) unsigned short As[128 * 32];
  __shared__ alignas(16) unsigned short Bs[128 * 32];
  const int tid = threadIdx.x;
  const int lane = tid & 63, wid = tid >> 6;
  const int bn = blockIdx.x & 31, bm = blockIdx.x >> 5;
  const int wr = wid >> 1, wc = wid & 1;

  f32x4 acc[4][4] = {};

  // staging: thread covers row (tid>>2) of a 64-row pass, k-chunk (tid&3)*8
  const unsigned short* Ag = A + (size_t)(bm * 128 + (tid >> 2)) * 512 + (tid & 3) * 8;
  const unsigned short* Bg = Bt + (size_t)(bn * 128 + (tid >> 2)) * 512 + (tid & 3) * 8;
  char* AsW = (char*)As + wid * 1024;  // wave-uniform LDS dest
  char* BsW = (char*)Bs + wid * 1024;

  const int laneRow = lane & 15;
  const int k0 = (lane >> 4) * 8;

  for (int kt = 0; kt < 16; ++kt) {
    __syncthreads();  // previous compute done before overwrite
    const unsigned short* a0 = Ag + kt * 32;
    const unsigned short* b0 = Bg + kt * 32;
    glds16(a0,            AsW);
    glds16(a0 + 64 * 512, AsW + 4096);
    glds16(b0,            BsW);
    glds16(b0 + 64 * 512, BsW + 4096);
    __syncthreads();  // compiler drains vmcnt before barrier

    short8 af[4], bf[4];
#pragma unroll
    for (int f = 0; f < 4; ++f)
      af[f] = *(const short8*)&As[(wr * 64 + f * 16 + laneRow) * 32 + k0];
#pragma unroll
    for (int f = 0; f < 4; ++f)
      bf[f] = *(const short8*)&Bs[(wc * 64 + f * 16 + laneRow) * 32 + k0];
#pragma unroll
    for (int fm = 0; fm < 4; ++fm)
#pragma unroll
      for (int fn = 0; fn < 4; ++fn)
        acc[fm][fn] = __builtin_amdgcn_mfma_f32_16x16x32_bf16(af[fm], bf[fn], acc[fm][fn], 0, 0, 0);
  }

  // epilogue: C/D layout col=lane&15, row=(lane>>4)*4+reg  [m89-verified]
  const int mg0 = bm * 128 + wr * 64, ng0 = bn * 128 + wc * 64;
#pragma unroll
  for (int fn = 0; fn < 4; ++fn) {
    const int col = ng0 + fn * 16 + laneRow;
    const float bo = Bo[col];
#pragma unroll
    for (int fm = 0; fm < 4; ++fm) {
      const int row0 = mg0 + fm * 16 + (lane >> 4) * 4;
#pragma unroll
      for (int r = 0; r < 4; ++r)
        C[(size_t)(row0 + r) * 4096 + col] = acc[fm][fn][r] + bo;
    }
  }
}

// ---------------------------------------------------------------------------
extern "C" void kernel_launch(void* const* d_in, const int* in_sizes, int n_in,
                              void* d_out, int out_size, void* d_ws, size_t ws_size,
                              hipStream_t stream) {
  (void)in_sizes; (void)n_in; (void)out_size; (void)ws_size;
  const int* x = (const int*)d_in[0];
  const float* Wxh = (const float*)d_in[1];
  const float* Whh = (const float*)d_in[2];
  const float* bh = (const float*)d_in[3];
  const float* Wo = (const float*)d_in[4];
  const float* Bo = (const float*)d_in[5];
  float* out = (float*)d_out;

  // workspace: WhhP2 512KB | WoT 4MB | hs 16MB  (total 20.5 MB)
  unsigned int* WhhP2 = (unsigned int*)d_ws;
  unsigned short* WoT = (unsigned short*)((char*)d_ws + (512u << 10));
  unsigned short* hs = (unsigned short*)((char*)d_ws + (512u << 10) + (4u << 20));

  hipLaunchKernelGGL(pack_whh, dim3(512), dim3(256), 0, stream, Whh, WhhP2);
  hipLaunchKernelGGL(transpose_wo, dim3(64, 8), dim3(256), 0, stream, Wo, WoT);
  hipLaunchKernelGGL(rnn_scan, dim3(64), dim3(512), 0, stream, x, Wxh, WhhP2, bh, hs);
  hipLaunchKernelGGL(gemm_out, dim3(4096), dim3(256), 0, stream, hs, WoT, Bo, out);
}